// Round 3
// baseline (160.212 us; speedup 1.0000x reference)
//
#include <hip/hip_runtime.h>

// Bicubic x0.5 antialiased resize, (32,3,512,512) f32 -> (32,3,256,256) f32.
// Separable 8-tap stride-2 conv; weights constant over output index (read
// from wt[i*256]); src index = mirror(2*o + i - 3).
//
// One fused kernel. Tile = 8 out rows x 256 out cols (full width).
// Phase A (H-pass): float4-coalesced global loads, register rolling window,
//   NO horizontal halo (mirror commutes with the H-pass), mid -> LDS.
// Phase B (W-pass): b64 LDS window reads (stride-514 pad => <=2-way banks,
//   free), float4 coalesced stores. Edge col-groups take a scalar mirror path.

#define H_IN   512
#define W_IN   512
#define H_OUT  256
#define W_OUT  256
#define BC     96
#define TAPS   8
#define OH_T   8
#define IN_ROWS (2 * OH_T + 6)   // 22
#define MID_STRIDE 514           // 512 + 2 pad: keeps b64 alignment, banks <=2-way

__device__ __forceinline__ int mir(int r, int n) {
    r = (r < 0) ? (-1 - r) : r;
    r = (r >= n) ? (2 * n - 1 - r) : r;
    return r;
}

__global__ __launch_bounds__(128) void resize_fused(const float* __restrict__ in,
                                                    const float* __restrict__ wh,
                                                    const float* __restrict__ ww,
                                                    float* __restrict__ out) {
    __shared__ float mid[OH_T * MID_STRIDE];   // 16448 B

    const int oht = blockIdx.x & 31;   // 32 row tiles
    const int bc  = blockIdx.x >> 5;   // 96 images
    const int t   = threadIdx.x;       // 128 threads

    // ---- Phase A: H-pass, thread t owns float4 col group t (cols 4t..4t+3)
    float KH[TAPS];
#pragma unroll
    for (int i = 0; i < TAPS; ++i) KH[i] = wh[i * H_OUT];

    const float4* src = (const float4*)(in + (size_t)bc * H_IN * W_IN) + t;
    const int rbase = 16 * oht - 3;

    float4 acc[OH_T];
#pragma unroll
    for (int k = 0; k < OH_T; ++k) acc[k] = make_float4(0.f, 0.f, 0.f, 0.f);

#pragma unroll
    for (int r = 0; r < IN_ROWS; ++r) {
        const int rm = mir(rbase + r, H_IN);
        const float4 x = src[(size_t)rm * (W_IN / 4)];
#pragma unroll
        for (int k = 0; k < OH_T; ++k) {
            const int i = r - 2 * k;          // compile-time
            if (0 <= i && i < TAPS) {
                const float kw = KH[i];
                acc[k].x += kw * x.x;
                acc[k].y += kw * x.y;
                acc[k].z += kw * x.z;
                acc[k].w += kw * x.w;
            }
        }
    }
#pragma unroll
    for (int k = 0; k < OH_T; ++k) {
        float2* m2 = (float2*)&mid[k * MID_STRIDE + 4 * t];  // 8B aligned
        m2[0] = make_float2(acc[k].x, acc[k].y);
        m2[1] = make_float2(acc[k].z, acc[k].w);
    }

    __syncthreads();

    // ---- Phase B: W-pass. Thread: row r = t&7, col groups cg0 and cg0+16
    // (8 output cols each). Window = 24 mid cols starting at 16*cg - 4.
    float KW[TAPS];
#pragma unroll
    for (int i = 0; i < TAPS; ++i) KW[i] = ww[i * W_OUT];

    const int r   = t & 7;
    const int cg0 = t >> 3;                 // 0..15
    const int oh  = 8 * oht + r;
    float* drow = out + ((size_t)bc * H_OUT + oh) * W_OUT;

#pragma unroll
    for (int cc = 0; cc < 2; ++cc) {
        const int cg = cg0 + 16 * cc;       // 0..31
        float win[24];
        if (cg == 0 || cg == 31) {
            // mirror edges, scalar LDS reads (2 of 32 groups)
#pragma unroll
            for (int w = 0; w < 24; ++w)
                win[w] = mid[r * MID_STRIDE + mir(16 * cg - 4 + w, W_IN)];
        } else {
            const float2* s2 = (const float2*)&mid[r * MID_STRIDE + 16 * cg - 4];
#pragma unroll
            for (int v = 0; v < 12; ++v) {
                const float2 d = s2[v];
                win[2 * v]     = d.x;
                win[2 * v + 1] = d.y;
            }
        }
        // output ow = 8*cg + m uses window floats w = 2m + j + 1
        float res[8];
#pragma unroll
        for (int m = 0; m < 8; ++m) {
            float s = 0.f;
#pragma unroll
            for (int j = 0; j < TAPS; ++j)
                s += KW[j] * win[2 * m + j + 1];
            res[m] = s;
        }
        float4* dv = (float4*)(drow + 8 * cg);   // 32B aligned
        dv[0] = make_float4(res[0], res[1], res[2], res[3]);
        dv[1] = make_float4(res[4], res[5], res[6], res[7]);
    }
}

extern "C" void kernel_launch(void* const* d_in, const int* in_sizes, int n_in,
                              void* d_out, int out_size, void* d_ws, size_t ws_size,
                              hipStream_t stream) {
    const float* in = (const float*)d_in[0];
    const float* w2 = (const float*)d_in[1];   // H weights (taps,256,...)
    const float* w3 = (const float*)d_in[3];   // W weights (identical table)
    float* out = (float*)d_out;
    (void)d_ws; (void)ws_size;

    // 96 bc * 32 row tiles = 3072 blocks, 128 threads
    resize_fused<<<BC * 32, 128, 0, stream>>>(in, w2, w3, out);
}